// Round 8
// baseline (241.065 us; speedup 1.0000x reference)
//
#include <hip/hip_runtime.h>
#include <hip/hip_bf16.h>
#include <cstdint>

typedef unsigned short ushort_t;
typedef __bf16 bf16x8 __attribute__((ext_vector_type(8)));
typedef float f32x4 __attribute__((ext_vector_type(4)));

#define B_   16
#define S_   512
#define D_   768
#define E_   128
#define USTRIDE 784   // Uext row stride (16B-aligned: 784*2=1568)

__device__ inline ushort_t f2b(float f) {
    uint32_t u = __builtin_bit_cast(uint32_t, f);
    uint32_t r = (u + 0x7fffu + ((u >> 16) & 1u)) >> 16;   // RNE
    return (ushort_t)r;
}
__device__ inline float b2f(ushort_t u) {
    uint32_t v = ((uint32_t)u) << 16;
    return __builtin_bit_cast(float, v);
}
__device__ inline float bl(uint32_t u) {
    uint32_t v = u << 16;
    return __builtin_bit_cast(float, v);
}
__device__ inline float bh(uint32_t u) {
    uint32_t v = u & 0xffff0000u;
    return __builtin_bit_cast(float, v);
}

// ---------------------------------------------------------------------------
// Prep (merged, one 256-thread unit per block):
//  [0,1536):      repE gather [2048,768] hid-only (float4 -> bf16)
//  [1536,2688):   W1-hid transposes ([768,768] per tower)
//  [2688,3264):   W2 transposes ([768,384] per tower)
//  [3264,3552):   bil transposes ([384,384] x2 -> BmatT rows 0..767)
//  [3552,3570):   embW1[tower][lab][n] = sum_k bf16(emb[lab,k])*bf16(W1[768+k,n])
//  [3570,3576):   tails: BmatT rows 768/769 (768 elems) + lWtT (768 elems)
//                 NOTE: 6 blocks x 256 = 1536 — round-7 used 2 and left
//                 lWtT/BmatT-row-769 poisoned (logits off by linear term).
// ---------------------------------------------------------------------------
__global__ __launch_bounds__(256) void prep_all(
    const float* __restrict__ hidden, const float* __restrict__ emb,
    const float* __restrict__ hW1, const float* __restrict__ tW1,
    const float* __restrict__ hW2, const float* __restrict__ tW2,
    const float* __restrict__ bil, const float* __restrict__ lW,
    const int* __restrict__ ent_start, const int* __restrict__ ent_label,
    ushort_t* __restrict__ repE, ushort_t* __restrict__ hW1T, ushort_t* __restrict__ tW1T,
    ushort_t* __restrict__ hW2T, ushort_t* __restrict__ tW2T,
    ushort_t* __restrict__ BmatT, ushort_t* __restrict__ lWtT,
    float* __restrict__ embW1, float* __restrict__ out)
{
    __shared__ float tp[32][33];
    const int u = blockIdx.x, t = threadIdx.x;
    if (u == 0 && t == 0) out[0] = 0.0f;

    if (u < 1536) {                               // repE gather (hid only)
        int idx = u * 256 + t;
        int row = idx / 192, q = idx - row * 192;
        int c = q * 4;
        int b = row >> 7;
        int st = ent_start[row];
        const float* srcp = hidden + ((size_t)(b * S_ + st) * D_ + c);
        float4 v = *reinterpret_cast<const float4*>(srcp);
        uint32_t lo = (uint32_t)f2b(v.x) | ((uint32_t)f2b(v.y) << 16);
        uint32_t hi = (uint32_t)f2b(v.z) | ((uint32_t)f2b(v.w) << 16);
        uint2 pk; pk.x = lo; pk.y = hi;
        *reinterpret_cast<uint2*>(repE + (size_t)idx * 4) = pk;
        return;
    }
    if (u < 3552) {                               // transposes
        const float* src; ushort_t* dst; int Rr, Cc, local;
        if (u < 2688) {                           // W1-hid [768,768]
            int u2 = u - 1536;
            int tower = u2 / 576; local = u2 - tower * 576;
            src = tower ? tW1 : hW1; dst = tower ? tW1T : hW1T;
            Rr = 768; Cc = 768;
        } else if (u < 3264) {                    // W2 [768,384]
            int u2 = u - 2688;
            int tower = u2 / 288; local = u2 - tower * 288;
            src = tower ? tW2 : hW2; dst = tower ? tW2T : hW2T;
            Rr = 768; Cc = 384;
        } else {                                  // bil [384,384] x2
            int u2 = u - 3264;
            int half = u2 / 144; local = u2 - half * 144;
            src = bil + (size_t)half * 147456; dst = BmatT + (size_t)half * 147456;
            Rr = 384; Cc = 384;
        }
        int nC = Cc >> 5;
        int tR = (local / nC) * 32, tC = (local - (local / nC) * nC) * 32;
        int tx = t & 31, ty = t >> 5;
#pragma unroll
        for (int r = 0; r < 4; ++r)
            tp[ty + r * 8][tx] = src[(size_t)(tR + ty + r * 8) * Cc + tC + tx];
        __syncthreads();
#pragma unroll
        for (int r = 0; r < 4; ++r)
            dst[(size_t)(tC + ty + r * 8) * Rr + tR + tx] = f2b(tp[tx][ty + r * 8]);
        return;
    }
    if (u < 3570) {                               // embW1 precompute
        int e = u - 3552;
        int z = e / 9, rem = e - z * 9;
        int lab = rem / 3, sub = rem - lab * 3;
        const float* W1 = z ? tW1 : hW1;
        int n = sub * 256 + t;
        float acc = 0.0f;
#pragma unroll 4
        for (int k = 0; k < 768; ++k) {
            float eb = b2f(f2b(emb[lab * D_ + k]));
            float wb = b2f(f2b(W1[(size_t)(768 + k) * 768 + n]));
            acc = fmaf(eb, wb, acc);
        }
        embW1[(size_t)(z * 3 + lab) * 768 + n] = acc;
        return;
    }
    int i2 = (u - 3570) * 256 + t;                // tails: i2 in [0,1536)
    if (i2 < 768) {                               // BmatT rows 768/769
        int o = i2 / 384, kk = i2 - o * 384;
        BmatT[(768 + o) * 384 + kk] = f2b(lW[kk * 2 + o]);
    } else if (i2 < 1536) {                       // lWtT [2,384]
        int j = i2 - 768;
        int o = j / 384, ii = j - o * 384;
        lWtT[o * 384 + ii] = f2b(lW[(384 + ii) * 2 + o]);
    }
}

// ---------------------------------------------------------------------------
// GEMM1: h/t1 = relu(repE @ W1hidT^T + embW1[lab[row]] + b1). K=768, N=768.
// 64x64 block tile, wave tile 32x32, BK=32, z = tower.
// ---------------------------------------------------------------------------
__global__ __launch_bounds__(256) void gemm1(
    const ushort_t* __restrict__ repE,
    const ushort_t* __restrict__ hW1T, const ushort_t* __restrict__ tW1T,
    const float* __restrict__ hb1, const float* __restrict__ tb1,
    const float* __restrict__ embW1, const int* __restrict__ ent_label,
    ushort_t* __restrict__ h1, ushort_t* __restrict__ t1)
{
    __shared__ ushort_t As[64 * 32];
    __shared__ ushort_t Bs[64 * 32];
    const int K = 768, N = 768;
    const ushort_t* Bt  = blockIdx.z ? tW1T : hW1T;
    const float*   bias = blockIdx.z ? tb1 : hb1;
    const float*   emb1 = embW1 + (size_t)blockIdx.z * 3 * 768;
    ushort_t*      out  = blockIdx.z ? t1 : h1;

    int t = threadIdx.x;
    int lane = t & 63, wave = t >> 6;
    int tileM = blockIdx.x * 64, tileN = blockIdx.y * 64;
    int wm = (wave >> 1) * 32, wn = (wave & 1) * 32;
    int l15 = lane & 15, quad = lane >> 4;
    int srow = t >> 2, sc8 = (t & 3) << 3;

    const ushort_t* gA = repE + (size_t)tileM * K;
    const ushort_t* gB = Bt   + (size_t)tileN * K;

    f32x4 acc[2][2];
#pragma unroll
    for (int a = 0; a < 2; ++a)
#pragma unroll
        for (int b = 0; b < 2; ++b) {
            acc[a][b][0] = 0.f; acc[a][b][1] = 0.f;
            acc[a][b][2] = 0.f; acc[a][b][3] = 0.f;
        }

    for (int k0 = 0; k0 < K; k0 += 32) {
        __builtin_amdgcn_global_load_lds(
            (const __attribute__((address_space(1))) void*)(gA + (size_t)srow * K + k0 + sc8),
            (__attribute__((address_space(3))) void*)(As + t * 8), 16, 0, 0);
        __builtin_amdgcn_global_load_lds(
            (const __attribute__((address_space(1))) void*)(gB + (size_t)srow * K + k0 + sc8),
            (__attribute__((address_space(3))) void*)(Bs + t * 8), 16, 0, 0);
        __syncthreads();
        bf16x8 af[2], bfr[2];
#pragma unroll
        for (int mi = 0; mi < 2; ++mi)
            af[mi] = *reinterpret_cast<const bf16x8*>(As + (wm + mi * 16 + l15) * 32 + quad * 8);
#pragma unroll
        for (int ni = 0; ni < 2; ++ni)
            bfr[ni] = *reinterpret_cast<const bf16x8*>(Bs + (wn + ni * 16 + l15) * 32 + quad * 8);
#pragma unroll
        for (int mi = 0; mi < 2; ++mi)
#pragma unroll
            for (int ni = 0; ni < 2; ++ni)
                acc[mi][ni] = __builtin_amdgcn_mfma_f32_16x16x32_bf16(af[mi], bfr[ni], acc[mi][ni], 0, 0, 0);
        __syncthreads();
    }

#pragma unroll
    for (int mi = 0; mi < 2; ++mi) {
        int gr = tileM + wm + mi * 16 + quad * 4;
        int lab[4];
#pragma unroll
        for (int r = 0; r < 4; ++r) lab[r] = ent_label[gr + r];
#pragma unroll
        for (int ni = 0; ni < 2; ++ni) {
            int gc = tileN + wn + ni * 16 + l15;
            float bb = bias[gc];
#pragma unroll
            for (int r = 0; r < 4; ++r) {
                float v = acc[mi][ni][r] + bb + emb1[(size_t)lab[r] * 768 + gc];
                v = fmaxf(v, 0.0f);
                out[(size_t)(gr + r) * N + gc] = f2b(v);
            }
        }
    }
}

// ---------------------------------------------------------------------------
// GEMM2 (generic): out = relu(A @ Bt^T + bias). 64x64 tile, z = tower.
// ---------------------------------------------------------------------------
__global__ __launch_bounds__(256) void gemm_lds(
    const ushort_t* __restrict__ A0, const ushort_t* __restrict__ A1,
    const ushort_t* __restrict__ Bt0, const ushort_t* __restrict__ Bt1,
    const float* __restrict__ bias0, const float* __restrict__ bias1,
    ushort_t* __restrict__ out0, ushort_t* __restrict__ out1,
    int M, int N, int K)
{
    __shared__ ushort_t As[64 * 32];
    __shared__ ushort_t Bs[64 * 32];
    const ushort_t* A   = blockIdx.z ? A1 : A0;
    const ushort_t* Bt  = blockIdx.z ? Bt1 : Bt0;
    const float*   bias = blockIdx.z ? bias1 : bias0;
    ushort_t*      out  = blockIdx.z ? out1 : out0;

    int t = threadIdx.x;
    int lane = t & 63, wave = t >> 6;
    int tileM = blockIdx.x * 64, tileN = blockIdx.y * 64;
    int wm = (wave >> 1) * 32, wn = (wave & 1) * 32;
    int l15 = lane & 15, quad = lane >> 4;
    int srow = t >> 2, sc8 = (t & 3) << 3;

    const ushort_t* gA = A  + (size_t)tileM * K;
    const ushort_t* gB = Bt + (size_t)tileN * K;

    f32x4 acc[2][2];
#pragma unroll
    for (int a = 0; a < 2; ++a)
#pragma unroll
        for (int b = 0; b < 2; ++b) {
            acc[a][b][0] = 0.f; acc[a][b][1] = 0.f;
            acc[a][b][2] = 0.f; acc[a][b][3] = 0.f;
        }

    for (int k0 = 0; k0 < K; k0 += 32) {
        __builtin_amdgcn_global_load_lds(
            (const __attribute__((address_space(1))) void*)(gA + (size_t)srow * K + k0 + sc8),
            (__attribute__((address_space(3))) void*)(As + t * 8), 16, 0, 0);
        __builtin_amdgcn_global_load_lds(
            (const __attribute__((address_space(1))) void*)(gB + (size_t)srow * K + k0 + sc8),
            (__attribute__((address_space(3))) void*)(Bs + t * 8), 16, 0, 0);
        __syncthreads();
        bf16x8 af[2], bfr[2];
#pragma unroll
        for (int mi = 0; mi < 2; ++mi)
            af[mi] = *reinterpret_cast<const bf16x8*>(As + (wm + mi * 16 + l15) * 32 + quad * 8);
#pragma unroll
        for (int ni = 0; ni < 2; ++ni)
            bfr[ni] = *reinterpret_cast<const bf16x8*>(Bs + (wn + ni * 16 + l15) * 32 + quad * 8);
#pragma unroll
        for (int mi = 0; mi < 2; ++mi)
#pragma unroll
            for (int ni = 0; ni < 2; ++ni)
                acc[mi][ni] = __builtin_amdgcn_mfma_f32_16x16x32_bf16(af[mi], bfr[ni], acc[mi][ni], 0, 0, 0);
        __syncthreads();
    }

#pragma unroll
    for (int mi = 0; mi < 2; ++mi) {
        int gr = tileM + wm + mi * 16 + quad * 4;
#pragma unroll
        for (int ni = 0; ni < 2; ++ni) {
            int gc = tileN + wn + ni * 16 + l15;
            if (gc < N) {
                float bb = bias[gc];
#pragma unroll
                for (int r = 0; r < 4; ++r) {
                    float v = fmaxf(acc[mi][ni][r] + bb, 0.0f);
                    out[(size_t)(gr + r) * N + gc] = f2b(v);
                }
            }
        }
    }
}

// ---------------------------------------------------------------------------
// GEMM3 (Uext = headsE @ BmatT^T, row stride USTRIDE) + fused tailLin.
// grid (32,14): by<13 gemm tile, by==13 tailLin (64 entities/block).
// ---------------------------------------------------------------------------
__global__ __launch_bounds__(256) void gemm3_tail(
    const ushort_t* __restrict__ headsE, const ushort_t* __restrict__ BmatT,
    const ushort_t* __restrict__ tailsE, const ushort_t* __restrict__ lWtT,
    ushort_t* __restrict__ Uext, float* __restrict__ tailLin)
{
    const int t = threadIdx.x;
    if (blockIdx.y == 13) {                       // tailLin
        int r = blockIdx.x * 64 + (t >> 2), q = t & 3;
        const uint32_t* tv = reinterpret_cast<const uint32_t*>(tailsE + (size_t)r * 384);
        const uint32_t* lw = reinterpret_cast<const uint32_t*>(lWtT);
        float p0 = 0.f, p1 = 0.f;
#pragma unroll 8
        for (int i = q * 48; i < q * 48 + 48; ++i) {
            uint32_t tu = tv[i];
            float tl = bl(tu), th = bh(tu);
            uint32_t l0 = lw[i], l1 = lw[192 + i];
            p0 += tl * bl(l0) + th * bh(l0);
            p1 += tl * bl(l1) + th * bh(l1);
        }
        p0 += __shfl_xor(p0, 1); p0 += __shfl_xor(p0, 2);
        p1 += __shfl_xor(p1, 1); p1 += __shfl_xor(p1, 2);
        if (q == 0) tailLin[2 * r]     = p0;
        if (q == 1) tailLin[2 * r + 1] = p1;
        return;
    }

    __shared__ ushort_t As[64 * 32];
    __shared__ ushort_t Bs[64 * 32];
    const int K = 384, N = 770;
    int lane = t & 63, wave = t >> 6;
    int tileM = blockIdx.x * 64, tileN = blockIdx.y * 64;
    int wm = (wave >> 1) * 32, wn = (wave & 1) * 32;
    int l15 = lane & 15, quad = lane >> 4;
    int srow = t >> 2, sc8 = (t & 3) << 3;

    const ushort_t* gA = headsE + (size_t)tileM * K;
    const ushort_t* gB = BmatT  + (size_t)tileN * K;

    f32x4 acc[2][2];
#pragma unroll
    for (int a = 0; a < 2; ++a)
#pragma unroll
        for (int b = 0; b < 2; ++b) {
            acc[a][b][0] = 0.f; acc[a][b][1] = 0.f;
            acc[a][b][2] = 0.f; acc[a][b][3] = 0.f;
        }

    for (int k0 = 0; k0 < K; k0 += 32) {
        __builtin_amdgcn_global_load_lds(
            (const __attribute__((address_space(1))) void*)(gA + (size_t)srow * K + k0 + sc8),
            (__attribute__((address_space(3))) void*)(As + t * 8), 16, 0, 0);
        __builtin_amdgcn_global_load_lds(
            (const __attribute__((address_space(1))) void*)(gB + (size_t)srow * K + k0 + sc8),
            (__attribute__((address_space(3))) void*)(Bs + t * 8), 16, 0, 0);
        __syncthreads();
        bf16x8 af[2], bfr[2];
#pragma unroll
        for (int mi = 0; mi < 2; ++mi)
            af[mi] = *reinterpret_cast<const bf16x8*>(As + (wm + mi * 16 + l15) * 32 + quad * 8);
#pragma unroll
        for (int ni = 0; ni < 2; ++ni)
            bfr[ni] = *reinterpret_cast<const bf16x8*>(Bs + (wn + ni * 16 + l15) * 32 + quad * 8);
#pragma unroll
        for (int mi = 0; mi < 2; ++mi)
#pragma unroll
            for (int ni = 0; ni < 2; ++ni)
                acc[mi][ni] = __builtin_amdgcn_mfma_f32_16x16x32_bf16(af[mi], bfr[ni], acc[mi][ni], 0, 0, 0);
        __syncthreads();
    }

#pragma unroll
    for (int mi = 0; mi < 2; ++mi) {
        int gr = tileM + wm + mi * 16 + quad * 4;
#pragma unroll
        for (int ni = 0; ni < 2; ++ni) {
            int gc = tileN + wn + ni * 16 + l15;
            if (gc < N) {
#pragma unroll
                for (int r = 0; r < 4; ++r)
                    Uext[(size_t)(gr + r) * USTRIDE + gc] = f2b(acc[mi][ni][r]);
            }
        }
    }
}

// ---------------------------------------------------------------------------
// Relations: 16-lane groups, uint4 loads (3 iters). Grid 2048.
// ---------------------------------------------------------------------------
__global__ __launch_bounds__(256) void rel16_kernel(
    const ushort_t* __restrict__ Uext, const ushort_t* __restrict__ tailsE,
    const float* __restrict__ tailLin, const float* __restrict__ lb,
    const int* __restrict__ rel_head, const int* __restrict__ rel_tail,
    const int* __restrict__ rel_label, float* __restrict__ out)
{
    __shared__ float wsum[4];
    const int t = threadIdx.x;
    int lane = t & 63, wave = t >> 6;
    int l = lane & 15, g = lane >> 4;
    float lb0 = lb[0], lb1 = lb[1];
    float lossAcc = 0.0f;

    int rel = (blockIdx.x * 4 + wave) * 4 + g;
    int b = rel >> 11;
    int h = rel_head[rel], tt = rel_tail[rel], lab = rel_label[rel];
    const uint4* uh4 = reinterpret_cast<const uint4*>(Uext + (size_t)(b * E_ + h) * USTRIDE);
    const uint4* tv4 = reinterpret_cast<const uint4*>(tailsE + (size_t)(b * E_ + tt) * 384);
    float a0 = 0.f, a1 = 0.f;
#pragma unroll
    for (int j = 0; j < 3; ++j) {
        int i = l + 16 * j;
        uint4 tu = tv4[i];
        uint4 u0 = uh4[i];
        uint4 u1 = uh4[48 + i];
        a0 += bl(tu.x) * bl(u0.x) + bh(tu.x) * bh(u0.x);
        a0 += bl(tu.y) * bl(u0.y) + bh(tu.y) * bh(u0.y);
        a0 += bl(tu.z) * bl(u0.z) + bh(tu.z) * bh(u0.z);
        a0 += bl(tu.w) * bl(u0.w) + bh(tu.w) * bh(u0.w);
        a1 += bl(tu.x) * bl(u1.x) + bh(tu.x) * bh(u1.x);
        a1 += bl(tu.y) * bl(u1.y) + bh(tu.y) * bh(u1.y);
        a1 += bl(tu.z) * bl(u1.z) + bh(tu.z) * bh(u1.z);
        a1 += bl(tu.w) * bl(u1.w) + bh(tu.w) * bh(u1.w);
    }
#pragma unroll
    for (int d = 1; d < 16; d <<= 1) {
        a0 += __shfl_xor(a0, d);
        a1 += __shfl_xor(a1, d);
    }
    if (l == 0) {
        const ushort_t* uhs = Uext + (size_t)(b * E_ + h) * USTRIDE;
        int te = b * E_ + tt;
        float l0v = a0 + tailLin[2 * te]     + b2f(uhs[768]) + lb0;
        float l1v = a1 + tailLin[2 * te + 1] + b2f(uhs[769]) + lb1;
        out[1 + 2 * rel]     = l0v;
        out[1 + 2 * rel + 1] = l1v;
        float m = fmaxf(l0v, l1v);
        lossAcc = m + logf(expf(l0v - m) + expf(l1v - m)) - (lab ? l1v : l0v);
    }
    lossAcc += __shfl_xor(lossAcc, 16);
    lossAcc += __shfl_xor(lossAcc, 32);
    if (lane == 0) wsum[wave] = lossAcc;
    __syncthreads();
    if (t == 0)
        atomicAdd(out, (wsum[0] + wsum[1] + wsum[2] + wsum[3]) * (1.0f / 32768.0f));
}

// ---------------------------------------------------------------------------
extern "C" void kernel_launch(void* const* d_in, const int* in_sizes, int n_in,
                              void* d_out, int out_size, void* d_ws, size_t ws_size,
                              hipStream_t stream)
{
    const float* hidden = (const float*)d_in[0];
    const float* emb    = (const float*)d_in[1];
    const float* hW1    = (const float*)d_in[2];
    const float* hb1    = (const float*)d_in[3];
    const float* hW2    = (const float*)d_in[4];
    const float* hb2    = (const float*)d_in[5];
    const float* tW1    = (const float*)d_in[6];
    const float* tb1    = (const float*)d_in[7];
    const float* tW2    = (const float*)d_in[8];
    const float* tb2    = (const float*)d_in[9];
    const float* bil    = (const float*)d_in[10];
    const float* lW     = (const float*)d_in[11];
    const float* lb     = (const float*)d_in[12];
    const int* ent_start = (const int*)d_in[13];
    const int* ent_label = (const int*)d_in[14];
    const int* rel_head  = (const int*)d_in[15];
    const int* rel_tail  = (const int*)d_in[16];
    const int* rel_label = (const int*)d_in[17];
    float* out = (float*)d_out;

    char* ws = (char*)d_ws;
    ushort_t* repE   = (ushort_t*)(ws + 0);         // [2048,768]
    ushort_t* hW1T   = (ushort_t*)(ws + 3145728);   // [768,768]
    ushort_t* tW1T   = (ushort_t*)(ws + 4325376);
    ushort_t* hW2T   = (ushort_t*)(ws + 5505024);   // [384,768]
    ushort_t* tW2T   = (ushort_t*)(ws + 6094848);
    ushort_t* BmatT  = (ushort_t*)(ws + 6684672);   // [770,384]
    ushort_t* lWtT   = (ushort_t*)(ws + 7276032);   // [2,384]
    float*    embW1  = (float*)   (ws + 7277568);   // [2,3,768] fp32
    ushort_t* h1     = (ushort_t*)(ws + 7296000);   // [2048,768]
    ushort_t* t1     = (ushort_t*)(ws + 10441728);
    ushort_t* headsE = (ushort_t*)(ws + 13587456);  // [2048,384]
    ushort_t* tailsE = (ushort_t*)(ws + 15160320);
    ushort_t* Uext   = (ushort_t*)(ws + 16733184);  // [2048,784]
    float*    tailLin= (float*)   (ws + 19944448);  // [2048,2]

    prep_all<<<3576, 256, 0, stream>>>(
        hidden, emb, hW1, tW1, hW2, tW2, bil, lW, ent_start, ent_label,
        repE, hW1T, tW1T, hW2T, tW2T, BmatT, lWtT, embW1, out);

    gemm1<<<dim3(32, 12, 2), 256, 0, stream>>>(
        repE, hW1T, tW1T, hb1, tb1, embW1, ent_label, h1, t1);

    gemm_lds<<<dim3(32, 6, 2), 256, 0, stream>>>(
        h1, t1, hW2T, tW2T, hb2, tb2, headsE, tailsE, 2048, 384, 768);

    gemm3_tail<<<dim3(32, 14, 1), 256, 0, stream>>>(
        headsE, BmatT, tailsE, lWtT, Uext, tailLin);

    rel16_kernel<<<2048, 256, 0, stream>>>(
        Uext, tailsE, tailLin, lb, rel_head, rel_tail, rel_label, out);
}